// Round 8
// baseline (455.752 us; speedup 1.0000x reference)
//
#include <hip/hip_runtime.h>

#define Tn 200
#define Dn 64
#define Hn 64
#define CC 16   // pipeline chunk (time steps per LDS buffer)

typedef _Float16 half2v __attribute__((ext_vector_type(2)));
typedef _Float16 half8v __attribute__((ext_vector_type(8)));
typedef unsigned int uint;

__device__ __forceinline__ float fast_sigmoid(float v) {
    return __builtin_amdgcn_rcpf(1.0f + __expf(-v));
}
__device__ __forceinline__ float fast_tanh(float v) {
    return 1.0f - 2.0f * __builtin_amdgcn_rcpf(1.0f + __expf(2.0f * v));
}
// Compiler-only fence (R7-verified): intra-wave DS ordering is HW in-order;
// only compiler reordering must be stopped. No s_waitcnt on the path.
__device__ __forceinline__ void cfence() {
    asm volatile("" ::: "memory");
}
// Producer-side drain: commit ds_writes before signaling the barrier.
__device__ __forceinline__ void lds_drain() {
    asm volatile("s_waitcnt lgkmcnt(0)" ::: "memory");
}
// Raw workgroup barrier with compiler fences (no vmcnt drain — the R6 lesson:
// never let a barrier drain the global-load/store queue).
__device__ __forceinline__ void bar() {
    cfence();
    __builtin_amdgcn_s_barrier();
    cfence();
}

// ============================================================================
// Fused producer/consumer AUGRU. One block per batch row, 2 waves:
//   wave 0 (producer): x-projection P_t = x_t·Wx + bias for a 16-step chunk,
//     fp16-packed into a ping-pong LDS ring. ~300 issue-cyc/step, no serial
//     deps -> runs ~5x faster than the consumer and always stays 1 chunk ahead.
//   wave 1 (consumer): the R7 recurrence loop, P read from LDS (ds_read_b64
//     issued alongside the s_h round trip -> latency fully hidden).
// Sync: producer {lds_drain; s_barrier} after each chunk; consumer matches
// barrier count (1 prologue + 1 per chunk except the last). Ping-pong makes
// chunk p (buf p&1) and the in-flight chunk p+1 (buf ~p&1) disjoint.
// Occupancy: 2048 blocks x 2 waves = 4 waves/SIMD -> launch_bounds(128,4);
// LDS 16.4 KB/block x 8 blocks = 131 KB/CU. All rows resident from t=0.
// ============================================================================
__global__ __launch_bounds__(128, 4)
void augru_pipe(const float* __restrict__ x,    // [B,T,64]
                const int*   __restrict__ slen, // [B]
                const float* __restrict__ att,  // [B,T]
                const float* __restrict__ gk,   // [128][128]
                const float* __restrict__ gb,   // [128]
                const float* __restrict__ ck,   // [128][64]
                const float* __restrict__ cb,   // [64]
                float*       __restrict__ out)  // [B,T,64]
{
    const int b    = blockIdx.x;
    const int tid  = threadIdx.x;
    const int wave = tid >> 6;
    const int j    = tid & 63;

    __shared__ __align__(16) _Float16 sP[2][CC][Hn][4];  // {pr,pu,pc,pad} fp16
    __shared__ __align__(16) _Float16 s_h[Hn];
    __shared__ __align__(16) _Float16 s_rh[Hn];

    const int len = slen[b];
    const int nch = (len + CC - 1) / CC;
    const float* xrow = x   + (size_t)b * Tn * Dn;
    const float* arow = att + (size_t)b * Tn;
    float*       orow = out + (size_t)b * Tn * Hn;

    if (wave == 0) {
        // ---------------- producer: x-part weights (K rows 0..63) ----------
        half2v wr[32], wu[32], wc[32];
#pragma unroll
        for (int m = 0; m < 32; ++m) {
            const int k = 2 * m;
            wr[m] = half2v{(_Float16)gk[(k + 0) * 128 + j],
                           (_Float16)gk[(k + 1) * 128 + j]};
            wu[m] = half2v{(_Float16)gk[(k + 0) * 128 + 64 + j],
                           (_Float16)gk[(k + 1) * 128 + 64 + j]};
            wc[m] = half2v{(_Float16)ck[(k + 0) * 64 + j],
                           (_Float16)ck[(k + 1) * 64 + j]};
        }
        const float br = gb[j], bu = gb[64 + j], bc = cb[j];

        for (int p = 0; p < nch; ++p) {
            const int t0 = p * CC, tend = min(len, t0 + CC);
            for (int t = t0; t < tend; ++t) {
                const float4* xv = (const float4*)(xrow + t * Dn);
                float r0 = br, r1 = 0.f, u0 = bu, u1 = 0.f, c0 = bc, c1 = 0.f;
#pragma unroll
                for (int kk = 0; kk < 16; ++kk) {
                    const float4 qx = xv[kk];
                    const half2v p0 = half2v{(_Float16)qx.x, (_Float16)qx.y};
                    const half2v p1 = half2v{(_Float16)qx.z, (_Float16)qx.w};
                    const int m = 2 * kk;
                    r0 = __builtin_amdgcn_fdot2(p0, wr[m],     r0, false);
                    r1 = __builtin_amdgcn_fdot2(p1, wr[m + 1], r1, false);
                    u0 = __builtin_amdgcn_fdot2(p0, wu[m],     u0, false);
                    u1 = __builtin_amdgcn_fdot2(p1, wu[m + 1], u1, false);
                    c0 = __builtin_amdgcn_fdot2(p0, wc[m],     c0, false);
                    c1 = __builtin_amdgcn_fdot2(p1, wc[m + 1], c1, false);
                }
                const half2v d0{(_Float16)(r0 + r1), (_Float16)(u0 + u1)};
                const half2v d1{(_Float16)(c0 + c1), (_Float16)0.0f};
                uint2 pk;
                pk.x = __builtin_bit_cast(uint, d0);
                pk.y = __builtin_bit_cast(uint, d1);
                *(uint2*)&sP[p & 1][t - t0][j][0] = pk;   // ds_write_b64
            }
            lds_drain();   // commit chunk p before signaling
            bar();
        }
    } else {
        // ---------------- consumer: h-part weights (K rows 64..127) --------
        half2v wr[32], wu[32], wc[32];
#pragma unroll
        for (int m = 0; m < 32; ++m) {
            const int k = 64 + 2 * m;
            wr[m] = half2v{(_Float16)gk[(k + 0) * 128 + j],
                           (_Float16)gk[(k + 1) * 128 + j]};
            wu[m] = half2v{(_Float16)gk[(k + 0) * 128 + 64 + j],
                           (_Float16)gk[(k + 1) * 128 + 64 + j]};
            wc[m] = half2v{(_Float16)ck[(k + 0) * 64 + j],
                           (_Float16)ck[(k + 1) * 64 + j]};
        }

        float h   = 0.0f;
        float a_n = (len > 0) ? arow[0] : 0.0f;   // 1-step att prefetch

        if (nch > 0) {
            bar();   // chunk 0 ready
            for (int p = 0; p < nch; ++p) {
                const int t0 = p * CC, tend = min(len, t0 + CC);
                for (int t = t0; t < tend; ++t) {
                    const float a = a_n;
                    a_n = arow[min(t + 1, len - 1)];

                    s_h[j] = (_Float16)h;
                    cfence();
                    // P read issues into the DS pipe behind the s_h write;
                    // data returns alongside the h-broadcast reads -> free.
                    const uint2 q = *(const uint2*)&sP[p & 1][t - t0][j][0];
                    const half2v g0 = __builtin_bit_cast(half2v, q.x);
                    const half2v g1 = __builtin_bit_cast(half2v, q.y);

                    float r0 = (float)g0[0], r1 = 0.f;
                    float u0 = (float)g0[1], u1 = 0.f;
                    const float pc = (float)g1[0];

                    const half8v* hv = (const half8v*)s_h;
#pragma unroll
                    for (int m8 = 0; m8 < 8; ++m8) {
                        const half8v v = hv[m8];
                        const half2v p0 = __builtin_shufflevector(v, v, 0, 1);
                        const half2v p1 = __builtin_shufflevector(v, v, 2, 3);
                        const half2v p2 = __builtin_shufflevector(v, v, 4, 5);
                        const half2v p3 = __builtin_shufflevector(v, v, 6, 7);
                        const int m = m8 * 4;
                        r0 = __builtin_amdgcn_fdot2(p0, wr[m + 0], r0, false);
                        r1 = __builtin_amdgcn_fdot2(p1, wr[m + 1], r1, false);
                        r0 = __builtin_amdgcn_fdot2(p2, wr[m + 2], r0, false);
                        r1 = __builtin_amdgcn_fdot2(p3, wr[m + 3], r1, false);
                        u0 = __builtin_amdgcn_fdot2(p0, wu[m + 0], u0, false);
                        u1 = __builtin_amdgcn_fdot2(p1, wu[m + 1], u1, false);
                        u0 = __builtin_amdgcn_fdot2(p2, wu[m + 2], u0, false);
                        u1 = __builtin_amdgcn_fdot2(p3, wu[m + 3], u1, false);
                    }
                    const float rg = fast_sigmoid(r0 + r1);
                    const float ug = fast_sigmoid(u0 + u1);

                    s_rh[j] = (_Float16)(rg * h);
                    cfence();

                    float c0 = pc, c1 = 0.f;
                    const half8v* rv = (const half8v*)s_rh;
#pragma unroll
                    for (int m8 = 0; m8 < 8; ++m8) {
                        const half8v v = rv[m8];
                        const half2v p0 = __builtin_shufflevector(v, v, 0, 1);
                        const half2v p1 = __builtin_shufflevector(v, v, 2, 3);
                        const half2v p2 = __builtin_shufflevector(v, v, 4, 5);
                        const half2v p3 = __builtin_shufflevector(v, v, 6, 7);
                        const int m = m8 * 4;
                        c0 = __builtin_amdgcn_fdot2(p0, wc[m + 0], c0, false);
                        c1 = __builtin_amdgcn_fdot2(p1, wc[m + 1], c1, false);
                        c0 = __builtin_amdgcn_fdot2(p2, wc[m + 2], c0, false);
                        c1 = __builtin_amdgcn_fdot2(p3, wc[m + 3], c1, false);
                    }
                    const float cg = fast_tanh(c0 + c1);

                    const float uh = (1.0f - a) * ug;
                    h = uh * h + (1.0f - uh) * cg;
                    orow[t * Hn + j] = h;
                    cfence();   // WAR vs next step's s_h/s_rh writes
                }
                if (p < nch - 1) bar();   // next chunk ready (matches producer)
            }
        }
    }

    // ---- zero tail: out[b, len:T, :] = 0 (both waves) ----
    float4 z;
    z.x = z.y = z.z = z.w = 0.0f;
    float* tail = orow + (size_t)len * Hn;
    const int total = (Tn - len) * Hn;
    for (int i = tid * 4; i < total; i += 128 * 4) {
        *(float4*)(tail + i) = z;
    }
}

extern "C" void kernel_launch(void* const* d_in, const int* in_sizes, int n_in,
                              void* d_out, int out_size, void* d_ws, size_t ws_size,
                              hipStream_t stream) {
    const float* x    = (const float*)d_in[0];
    const int*   slen = (const int*)  d_in[1];
    const float* att  = (const float*)d_in[2];
    const float* gk   = (const float*)d_in[3];
    const float* gb   = (const float*)d_in[4];
    const float* ck   = (const float*)d_in[5];
    const float* cb   = (const float*)d_in[6];
    float* out = (float*)d_out;

    const int B = in_sizes[1];  // 2048
    augru_pipe<<<B, 128, 0, stream>>>(x, slen, att, gk, gb, ck, cb, out);
}